// Round 7
// baseline (126.576 us; speedup 1.0000x reference)
//
#include <hip/hip_runtime.h>

// SliceNApply: bilateral-grid trilinear slice + per-pixel 3x4 affine apply.
// FP32 tensors. B=4, C=12, D=8, Hg=Wg=16, H=W=1024.
//
// R7 = R6 (scratch-proof scalar discipline, verified: kernel 190->~39us) +
//  - 2 px/lane via float2 (named .x/.y only, NO arrays): 8 iters, half the
//    VMEM instructions, x-weights hoisted (loop-invariant per lane).
//  - depth-1 software pipeline with named cur/nxt register sets, loop
//    unrolled by 2 in source: iter i+1's guide/fr loads issue before iter
//    i's FMA chain -> global latency hidden at 3 waves/SIMD.
//  Kept verified: bf16 z-pair packing (12 ds_read_b128/px), quadrant waves
//  + ZSTRIDE=132 -> ~0 bank conflicts, __launch_bounds__(256,3).

#define ZSTRIDE 132   // 9 cells * 12 ch = 108 dwords + 24 pad (132 % 32 == 4)

static __device__ __forceinline__ unsigned short f2bf(float f) {
    unsigned int u = __float_as_uint(f);
    u += ((u >> 16) & 1u) + 0x7FFFu;
    return (unsigned short)(u >> 16);
}
static __device__ __forceinline__ float bf_lo(unsigned int d) {
    return __uint_as_float(d << 16);
}
static __device__ __forceinline__ float bf_hi(unsigned int d) {
    return __uint_as_float(d & 0xFFFF0000u);
}

static __device__ __forceinline__ void corner_fma(
    const unsigned int* __restrict__ cp, float wl, float wh,
    float& a0, float& a1, float& a2, float& a3)
{
    const uint4 d = *reinterpret_cast<const uint4*>(cp);
    a0 = fmaf(wl, bf_lo(d.x), a0); a0 = fmaf(wh, bf_hi(d.x), a0);
    a1 = fmaf(wl, bf_lo(d.y), a1); a1 = fmaf(wh, bf_hi(d.y), a1);
    a2 = fmaf(wl, bf_lo(d.z), a2); a2 = fmaf(wh, bf_hi(d.z), a2);
    a3 = fmaf(wl, bf_lo(d.w), a3); a3 = fmaf(wh, bf_hi(d.w), a3);
}

// full trilinear slice + affine apply for ONE pixel (all scalar state)
static __device__ __forceinline__ void pixel_compute(
    const unsigned int* __restrict__ lds,
    int cof0, int cof1, int cof2, int cof3,
    float g, float u0, float u1, float v0, float v1,
    float f0, float f1, float f2,
    float& o0, float& o1, float& o2)
{
    const float gz = g * 8.0f - 0.5f;
    int s = (int)floorf(gz);
    s = min(max(s, 0), 7);
    const float wz = fmaxf(gz - (float)s, 0.0f);
    const float zl = 1.0f - wz, zh = wz;
    const unsigned int* sb = lds + s * ZSTRIDE;

    const float w00 = v0 * u0, w01 = v0 * u1;
    const float w10 = v1 * u0, w11 = v1 * u1;
    const float wl0 = w00 * zl, wh0 = w00 * zh;
    const float wl1 = w01 * zl, wh1 = w01 * zh;
    const float wl2 = w10 * zl, wh2 = w10 * zh;
    const float wl3 = w11 * zl, wh3 = w11 * zh;

    {
        float a0 = 0.f, a1 = 0.f, a2 = 0.f, a3 = 0.f;
        corner_fma(sb + cof0, wl0, wh0, a0, a1, a2, a3);
        corner_fma(sb + cof1, wl1, wh1, a0, a1, a2, a3);
        corner_fma(sb + cof2, wl2, wh2, a0, a1, a2, a3);
        corner_fma(sb + cof3, wl3, wh3, a0, a1, a2, a3);
        o0 = fmaf(a0, f0, fmaf(a1, f1, fmaf(a2, f2, a3)));
    }
    {
        float a0 = 0.f, a1 = 0.f, a2 = 0.f, a3 = 0.f;
        corner_fma(sb + cof0 + 4, wl0, wh0, a0, a1, a2, a3);
        corner_fma(sb + cof1 + 4, wl1, wh1, a0, a1, a2, a3);
        corner_fma(sb + cof2 + 4, wl2, wh2, a0, a1, a2, a3);
        corner_fma(sb + cof3 + 4, wl3, wh3, a0, a1, a2, a3);
        o1 = fmaf(a0, f0, fmaf(a1, f1, fmaf(a2, f2, a3)));
    }
    {
        float a0 = 0.f, a1 = 0.f, a2 = 0.f, a3 = 0.f;
        corner_fma(sb + cof0 + 8, wl0, wh0, a0, a1, a2, a3);
        corner_fma(sb + cof1 + 8, wl1, wh1, a0, a1, a2, a3);
        corner_fma(sb + cof2 + 8, wl2, wh2, a0, a1, a2, a3);
        corner_fma(sb + cof3 + 8, wl3, wh3, a0, a1, a2, a3);
        o2 = fmaf(a0, f0, fmaf(a1, f1, fmaf(a2, f2, a3)));
    }
}

__global__ __launch_bounds__(256, 3) void slice_apply(
    const float* __restrict__ grid,   // [4][12][8][16][16]
    const float* __restrict__ guide,  // [4][1][1024][1024]
    const float* __restrict__ fr,     // [4][3][1024][1024]
    float* __restrict__ out)          // [4][3][1024][1024]
{
    __shared__ __align__(16) unsigned int lds[8 * ZSTRIDE];

    const int b     = blockIdx.y;
    const int tileX = blockIdx.x & 15;
    const int tileY = blockIdx.x >> 4;
    const int t     = threadIdx.x;

    // ---- stage grid slice into LDS, z-pair packed as bf16x2 ----
    {
        const int py0 = min(max(tileY - 1, 0), 15);
        const int py1 = tileY;
        const int py2 = min(tileY + 1, 15);
        const int px0 = min(max(tileX - 1, 0), 15);
        const int px1 = tileX;
        const int px2 = min(tileX + 1, 15);
        for (int e = t; e < 8 * 9 * 12; e += 256) {
            const int c    = e % 12;
            const int cell = (e / 12) % 9;
            const int s    = e / 108;
            const int s2   = min(s + 1, 7);
            const int gy3  = cell / 3;
            const int gx3  = cell % 3;
            const int ry = (gy3 == 0) ? py0 : ((gy3 == 1) ? py1 : py2);
            const int rx = (gx3 == 0) ? px0 : ((gx3 == 1) ? px1 : px2);
            const int cb = (b * 12 + c) * 8;
            const int sp = ry * 16 + rx;
            const float lo = grid[(cb + s)  * 256 + sp];
            const float hi = grid[(cb + s2) * 256 + sp];
            lds[s * ZSTRIDE + cell * 12 + c] =
                (unsigned int)f2bf(lo) | ((unsigned int)f2bf(hi) << 16);
        }
    }
    __syncthreads();

    // wave = quadrant (32x32 px); lane -> 2 px in x; 16 x-lanes * 4 rows
    const int w    = t >> 6;
    const int l    = t & 63;
    const int by   = w >> 1;            // wave-uniform
    const int bx   = w & 1;             // wave-uniform
    const int row  = l >> 4;            // 0..3
    const int xi   = (l & 15) * 2;      // 0..30, even
    const int xloc = bx * 32 + xi;      // x within tile
    const int xg   = tileX * 64 + xloc; // global x (even -> float2 aligned)

    // loop-invariant x weights for both pixels
    const float wxa = ((float)xloc + 0.5f) * 0.015625f + (0.5f - (float)bx);
    const float wxb = ((float)xloc + 1.5f) * 0.015625f + (0.5f - (float)bx);
    const float u00 = 1.0f - wxa, u01 = wxa;
    const float u10 = 1.0f - wxb, u11 = wxb;

    const int cof0 = ((by + 0) * 3 + (bx + 0)) * 12;
    const int cof1 = ((by + 0) * 3 + (bx + 1)) * 12;
    const int cof2 = ((by + 1) * 3 + (bx + 0)) * 12;
    const int cof3 = ((by + 1) * 3 + (bx + 1)) * 12;

    const int lyb = by * 32 + row;            // tile-local y at iter 0
    const int yb  = tileY * 64 + lyb;         // global y at iter 0

    // offsets at iter i: +i*4 rows
    #define GOFS(i) ((b * 1024 + yb + (i) * 4) * 1024 + xg)
    #define FOFS(i) (((b * 3) * 1024 + yb + (i) * 4) * 1024 + xg)

    // ---- software pipeline (depth 1), named register sets, no arrays ----
    float2 gc, c0, c1, c2, gn, n0, n1, n2;
    {
        const int go = GOFS(0), fo = FOFS(0);
        gc = *reinterpret_cast<const float2*>(guide + go);
        c0 = *reinterpret_cast<const float2*>(fr + fo);
        c1 = *reinterpret_cast<const float2*>(fr + fo + 1048576);
        c2 = *reinterpret_cast<const float2*>(fr + fo + 2097152);
    }

    for (int i = 0; i < 8; i += 2) {
        // issue loads for iter i+1
        {
            const int go = GOFS(i + 1), fo = FOFS(i + 1);
            gn = *reinterpret_cast<const float2*>(guide + go);
            n0 = *reinterpret_cast<const float2*>(fr + fo);
            n1 = *reinterpret_cast<const float2*>(fr + fo + 1048576);
            n2 = *reinterpret_cast<const float2*>(fr + fo + 2097152);
        }
        // compute + store iter i
        {
            const int ly = lyb + i * 4;
            const float wy = ((float)ly + 0.5f) * 0.015625f + (0.5f - (float)by);
            const float v1 = wy, v0 = 1.0f - wy;
            float oa0, oa1, oa2, ob0, ob1, ob2;
            pixel_compute(lds, cof0, cof1, cof2, cof3, gc.x, u00, u01, v0, v1,
                          c0.x, c1.x, c2.x, oa0, oa1, oa2);
            pixel_compute(lds, cof0, cof1, cof2, cof3, gc.y, u10, u11, v0, v1,
                          c0.y, c1.y, c2.y, ob0, ob1, ob2);
            const int fo = FOFS(i);
            const float2 O0 = {oa0, ob0}, O1 = {oa1, ob1}, O2 = {oa2, ob2};
            *reinterpret_cast<float2*>(out + fo)           = O0;
            *reinterpret_cast<float2*>(out + fo + 1048576) = O1;
            *reinterpret_cast<float2*>(out + fo + 2097152) = O2;
        }
        // issue loads for iter i+2 (clamped; extras discarded after loop)
        {
            const int j  = min(i + 2, 7);
            const int go = GOFS(j), fo = FOFS(j);
            gc = *reinterpret_cast<const float2*>(guide + go);
            c0 = *reinterpret_cast<const float2*>(fr + fo);
            c1 = *reinterpret_cast<const float2*>(fr + fo + 1048576);
            c2 = *reinterpret_cast<const float2*>(fr + fo + 2097152);
        }
        // compute + store iter i+1
        {
            const int ly = lyb + (i + 1) * 4;
            const float wy = ((float)ly + 0.5f) * 0.015625f + (0.5f - (float)by);
            const float v1 = wy, v0 = 1.0f - wy;
            float oa0, oa1, oa2, ob0, ob1, ob2;
            pixel_compute(lds, cof0, cof1, cof2, cof3, gn.x, u00, u01, v0, v1,
                          n0.x, n1.x, n2.x, oa0, oa1, oa2);
            pixel_compute(lds, cof0, cof1, cof2, cof3, gn.y, u10, u11, v0, v1,
                          n0.y, n1.y, n2.y, ob0, ob1, ob2);
            const int fo = FOFS(i + 1);
            const float2 O0 = {oa0, ob0}, O1 = {oa1, ob1}, O2 = {oa2, ob2};
            *reinterpret_cast<float2*>(out + fo)           = O0;
            *reinterpret_cast<float2*>(out + fo + 1048576) = O1;
            *reinterpret_cast<float2*>(out + fo + 2097152) = O2;
        }
    }
    #undef GOFS
    #undef FOFS
}

extern "C" void kernel_launch(void* const* d_in, const int* in_sizes, int n_in,
                              void* d_out, int out_size, void* d_ws, size_t ws_size,
                              hipStream_t stream) {
    const float* grid  = (const float*)d_in[0];
    const float* guide = (const float*)d_in[1];
    const float* fr    = (const float*)d_in[2];
    float* out = (float*)d_out;

    dim3 g(256, 4);   // 16x16 tiles of 64x64 px, 4 batches
    dim3 blk(256);
    hipLaunchKernelGGL(slice_apply, g, blk, 0, stream, grid, guide, fr, out);
}